// Round 5
// baseline (704.898 us; speedup 1.0000x reference)
//
#include <hip/hip_runtime.h>
#include <math.h>

// Problem constants (fixed by setup_inputs)
constexpr int B_ = 4, S_ = 8192, D_ = 1024, H_ = 1024, O_ = 1024;

typedef float f32x4  __attribute__((ext_vector_type(4)));
typedef float f32x16 __attribute__((ext_vector_type(16)));
typedef int   i32x4  __attribute__((ext_vector_type(4)));
typedef int   i32x8  __attribute__((ext_vector_type(8)));

__device__ __forceinline__ float softplusf(float x) {
    if (x > 20.f) return x;
    if (x < -20.f) return expf(x);
    return log1pf(expf(x));
}

// ---------------------------------------------------------------------------
// fp32 -> fp8 e4m3 for x, written in MFMA-fragment-tiled order:
//   addr = pp*262144 + c*16384 + (r>>5)*2048 + j*1024 + half*512 + (r&31)*16
//   (pp = s-panel of 256 rows, c = k-chunk of 64, j = (k>>4)&1,
//    half = (k>>5)&1).  GEMM A-loads become base + lane*16 (fully coalesced
//   dwordx4), no LDS round-trip for A at all.  Verified byte-exact against
//   the round-3 (passing) LDS fragment addressing.
// ---------------------------------------------------------------------------
__global__ __launch_bounds__(256) void cvt_x_tiled(
    const float* __restrict__ x, unsigned char* __restrict__ xq)
{
    const int blk = blockIdx.x;          // pp*4 + rq
    const int pp  = blk >> 2;
    const int rq  = blk & 3;
    const int rl  = threadIdx.x >> 2;    // 0..63
    const int seg = threadIdx.x & 3;     // 16-float segment within 64-k chunk
    const int r   = rq * 64 + rl;        // 0..255 (row within panel)

    const float* src = x + ((size_t)(pp * 256 + r)) * 1024 + seg * 16;
    unsigned char* dst = xq + (size_t)pp * 262144
                       + (r >> 5) * 2048 + (seg & 1) * 1024
                       + (((seg >> 1) * 32 + (r & 31))) * 16;
    #pragma unroll 4
    for (int c = 0; c < 16; ++c) {
        const float4* s4 = (const float4*)(src + c * 64);
        float4 f0 = s4[0], f1 = s4[1], f2 = s4[2], f3 = s4[3];
        int d0 = __builtin_amdgcn_cvt_pk_fp8_f32(f0.x, f0.y, 0, false);
        d0     = __builtin_amdgcn_cvt_pk_fp8_f32(f0.z, f0.w, d0, true);
        int d1 = __builtin_amdgcn_cvt_pk_fp8_f32(f1.x, f1.y, 0, false);
        d1     = __builtin_amdgcn_cvt_pk_fp8_f32(f1.z, f1.w, d1, true);
        int d2 = __builtin_amdgcn_cvt_pk_fp8_f32(f2.x, f2.y, 0, false);
        d2     = __builtin_amdgcn_cvt_pk_fp8_f32(f2.z, f2.w, d2, true);
        int d3 = __builtin_amdgcn_cvt_pk_fp8_f32(f3.x, f3.y, 0, false);
        d3     = __builtin_amdgcn_cvt_pk_fp8_f32(f3.z, f3.w, d3, true);
        *(int4*)(dst + (size_t)c * 16384) = make_int4(d0, d1, d2, d3);
    }
}

// fp32 -> fp8 e4m3 for w_in (scale 16, compensated by 2^-4 B-scale in MFMA),
// row-major (LDS-staged in the GEMM). 8 elems/thread.
__global__ __launch_bounds__(256) void cvt_w8(
    const float* __restrict__ src, unsigned char* __restrict__ dst, int n8)
{
    int i = blockIdx.x * blockDim.x + threadIdx.x;
    if (i >= n8) return;
    const float4* s = (const float4*)src + (size_t)i * 2;
    float4 a = s[0], b = s[1];
    int lo = __builtin_amdgcn_cvt_pk_fp8_f32(a.x * 16.f, a.y * 16.f, 0, false);
    lo     = __builtin_amdgcn_cvt_pk_fp8_f32(a.z * 16.f, a.w * 16.f, lo, true);
    int hi = __builtin_amdgcn_cvt_pk_fp8_f32(b.x * 16.f, b.y * 16.f, 0, false);
    hi     = __builtin_amdgcn_cvt_pk_fp8_f32(b.z * 16.f, b.w * 16.f, hi, true);
    ((int2*)dst)[i] = make_int2(lo, hi);
}

// ---------------------------------------------------------------------------
// Exact F in fp32 (one wave per (b,h)):
//   F = (1+e^{-i}) / ((1+e^{-f}) + (1+e^{-i}))  at s = S-1
// ---------------------------------------------------------------------------
__global__ __launch_bounds__(256) void f_exact(
    const float* __restrict__ x, const float* __restrict__ w_in,
    float* __restrict__ F_ws)
{
    const int lane = threadIdx.x & 63;
    const int pair = blockIdx.x * 4 + (threadIdx.x >> 6);   // 0..4095
    const int b = pair >> 10, h = pair & (H_ - 1);
    const float* xr = x + ((size_t)b * S_ + (S_ - 1)) * D_;
    const float* wf = w_in + (size_t)h * D_;
    const float* wi = wf + (size_t)H_ * D_;
    float sf = 0.f, si = 0.f;
    for (int k = lane; k < D_; k += 64) {
        float xv = xr[k];
        sf = fmaf(xv, wf[k], sf);
        si = fmaf(xv, wi[k], si);
    }
    #pragma unroll
    for (int off = 32; off > 0; off >>= 1) {
        sf += __shfl_xor(sf, off, 64);
        si += __shfl_xor(si, off, 64);
    }
    if (lane == 0) {
        float af1 = 1.f + expf(-sf), ai1 = 1.f + expf(-si);
        F_ws[(size_t)b * H_ + h] = ai1 / (af1 + ai1);
    }
}

// ---------------------------------------------------------------------------
// MX-fp8 MFMA GEMM (z = x @ w_in^T, 3 gates) fused with elementwise chain and
// s-reduction.
//   Round-5 = round-4 design + two correctness fixes (never benched):
//   (a) prologue drain vmcnt(6)->vmcnt(4): D(0) must land before ldB(0)
//       (vmcnt(N) retires only the oldest outstanding ops, m135);
//   (b) lgkmcnt(0)+sched_barrier before every main-loop s_barrier: closes
//       the ring-slot race (ldB(c) ds_reads vs issueB(c+4) overwrite were
//       in the same inter-barrier window).
//   Design: A bypasses LDS entirely (fragment-tiled global loads, L1/L2-hot);
//   LDS stages ONLY B: 12 KB/chunk, 4-deep ring (48 KB). LDS traffic/chunk
//   drops 108KB -> 60KB (below the 825-cy MFMA floor -> matrix pipe bound).
//   One barrier/chunk; per-wave counted vmcnt ledger (below); register-
//   double-buffered A (afE/afO) and B (bfE/bfO) fragments.
// ---------------------------------------------------------------------------
constexpr int BM = 256, BN = 64, BK = 64;          // BK in fp8 bytes
constexpr int BUF_BYTES = 3 * BN * BK;             // 12288 (B only)
constexpr int NBUF = 4;
constexpr int SMEM_BYTES = NBUF * BUF_BYTES;       // 49152

__global__ __launch_bounds__(512, 2) void gemm_fused_fp8(
    const unsigned char* __restrict__ xq, const unsigned char* __restrict__ wq,
    float* __restrict__ acc_ws)
{
    extern __shared__ unsigned char smem[];        // 48 KB ring (4 B-buffers)

    // decode: id = ((pl*16 + hb) * 8) + c8 ; panel = c8*16 + pl
    // (16 h-tiles sharing an A panel -> same XCD under round-robin mod 8)
    const int id = blockIdx.x;
    const int c8 = id & 7;
    const int q  = id >> 3;
    const int hb = q & 15;
    const int pl = q >> 4;
    const int panel = c8 * 16 + pl;       // 0..127

    const int h0   = hb * BN;
    const int tid  = threadIdx.x;
    const int lane = tid & 63;
    const int wid  = tid >> 6;   // 0..7
    const int wm   = wid >> 1;   // 0..3 : s offset wm*64
    const int wn   = wid & 1;    // 0..1 : h offset wn*32
    const int l31  = lane & 31;
    const int half = lane >> 5;  // k-half for MFMA operand

    // --- B staging: v = wid*2 + j (wid<6); gate v>>2, rows (v&3)*16..+15 ---
    const unsigned char* gpb[2];
    {
        const int rl = lane >> 2;        // row within 16-row chunk
        const int sp = lane & 3;         // dest 16B slot within 64B row
        const int qq = sp ^ ((rl >> 1) & 3);   // swizzled source slot
        #pragma unroll
        for (int j = 0; j < 2; ++j) {
            int v = wid * 2 + j;         // 0..11 valid for wid<6
            if (v < 12) {
                gpb[j] = wq + (size_t)(v >> 2) * (H_ * D_)
                            + (size_t)(h0 + (v & 3) * 16 + rl) * D_ + qq * 16;
            } else {
                gpb[j] = wq;             // waves 6,7: never issued
            }
        }
    }

    // --- A: tiled global base (fragment layout; see cvt_x_tiled) ----------
    const unsigned char* abase = xq + (size_t)panel * 262144
                               + wm * 4096 + lane * 16;

    // --- B fragment byte-offsets (swizzle term g/t-independent) -----------
    const int g2 = (l31 >> 1) & 3;
    const int sA = ((half * 2) ^ g2) * 16;
    const int bof0  = (wn * 32 + l31) * 64 + sA;   // + g*4096
    const int bof0x = bof0 ^ 16;

    f32x16 acc[3][2] = {};   // [gate][m-tile]

    auto issueB = [&](int cc) {
        if (wid < 6) {
            unsigned char* lb = smem + (cc & 3) * BUF_BYTES + wid * 2048;
            #pragma unroll
            for (int j = 0; j < 2; ++j) {
                __builtin_amdgcn_global_load_lds(
                    (const __attribute__((address_space(1))) void*)gpb[j],
                    (__attribute__((address_space(3))) void*)(lb + j * 1024),
                    16, 0, 0);
                gpb[j] += BK;
            }
        }
    };
    auto ldA = [&](int cc, i32x8* af) {
        const unsigned char* p = abase + (size_t)cc * 16384;
        i32x4 a0 = *(const i32x4*)(p);
        i32x4 a1 = *(const i32x4*)(p + 1024);
        i32x4 a2 = *(const i32x4*)(p + 2048);
        i32x4 a3 = *(const i32x4*)(p + 3072);
        af[0] = (i32x8){a0.x, a0.y, a0.z, a0.w, a1.x, a1.y, a1.z, a1.w};
        af[1] = (i32x8){a2.x, a2.y, a2.z, a2.w, a3.x, a3.y, a3.z, a3.w};
    };
    auto rd8 = [](const unsigned char* base, int o0, int o1) -> i32x8 {
        i32x4 lo = *(const i32x4*)(base + o0);
        i32x4 hi = *(const i32x4*)(base + o1);
        i32x8 r = {lo.x, lo.y, lo.z, lo.w, hi.x, hi.y, hi.z, hi.w};
        return r;
    };
    auto ldB = [&](int cc, i32x8* bf) {
        const unsigned char* bp = smem + (cc & 3) * BUF_BYTES;
        bf[0] = rd8(bp, bof0,        bof0x);
        bf[1] = rd8(bp, bof0 + 4096, bof0x + 4096);
        bf[2] = rd8(bp, bof0 + 8192, bof0x + 8192);
    };

    i32x8 afE[2], afO[2], bfE[3], bfO[3];

    // --- prologue: A(0) + D(0),D(1),D(2) in flight; frags of chunk 0 ------
    ldA(0, afE);                 // FIFO (wid<6): A0(4), D0(2), D1(2), D2(2)
    issueB(0); issueB(1); issueB(2);
    // drain A0+D0 (oldest 6 of 10) -> vmcnt(4).  wid>=6: 4 outstanding, passes.
    asm volatile("s_waitcnt vmcnt(4)" ::: "memory");
    __builtin_amdgcn_sched_barrier(0);
    __builtin_amdgcn_s_barrier();          // all waves' D(0) landed
    __builtin_amdgcn_sched_barrier(0);
    ldB(0, bfE);

    // vmcnt ledger (wid<6), entry of chunk c>=1: [D(c+1)2, A(c)4, D(c+2)2]=8.
    // Body issues A(c+1)4 then D(c+3)2, then drains through D(c+1):
    //   c==0: entry [D1,D2]=4, +A1+D3=10 -> drain D1 -> vmcnt(8)
    //   1<=c<=12: 8+6=14 -> drain D(c+1) -> vmcnt(12)
    //   c==13: no D16; [D14,A13,D15]=8 +A14=12 -> drain D14 -> vmcnt(10)
    //   c==14: [D15,A14]=6 +A15=10 -> drain D15 -> vmcnt(8)
    //   c==15: no reads, no manual wait (compiler drains A15 before MFMA)
    // wid>=6 carry only own A-loads (<=8 outstanding): all waits pass.
    // Ring safety: ldB(c) reads (slot c&3) drained at pre-barrier(c) by the
    // lgkmcnt(0); overwrite issueB(c+4) is post-barrier(c).  DMA D(c+1)
    // landed at barrier(c) per ledger; first read ldB(c+1) post-barrier(c).
    constexpr int NC = D_ / BK;   // 16 chunks
    #pragma unroll
    for (int c = 0; c < NC; ++c) {
        i32x8* afC = (c & 1) ? afO : afE;
        i32x8* bfC = (c & 1) ? bfO : bfE;
        i32x8* afN = (c & 1) ? afE : afO;
        i32x8* bfN = (c & 1) ? bfE : bfO;

        if (c + 1 < NC) ldA(c + 1, afN);
        if (c + 3 < NC) issueB(c + 3);

        if (c + 1 < NC) {
            if (wid < 6) {
                if (c == 0)        { asm volatile("s_waitcnt vmcnt(8)"  ::: "memory"); }
                else if (c <= 12)  { asm volatile("s_waitcnt vmcnt(12)" ::: "memory"); }
                else if (c == 13)  { asm volatile("s_waitcnt vmcnt(10)" ::: "memory"); }
                else               { asm volatile("s_waitcnt vmcnt(8)"  ::: "memory"); }
            } else {
                asm volatile("s_waitcnt vmcnt(8)" ::: "memory");
            }
            // drain this wave's ds_reads (ldB(c), issued one MFMA cluster
            // ago) so the slot can be overwritten after the barrier.
            asm volatile("s_waitcnt lgkmcnt(0)" ::: "memory");
            __builtin_amdgcn_sched_barrier(0);
            __builtin_amdgcn_s_barrier();      // all waves' D(c+1) landed
            __builtin_amdgcn_sched_barrier(0);
            ldB(c + 1, bfN);                   // hides under MFMAs below
        }

        __builtin_amdgcn_s_setprio(1);
        #pragma unroll
        for (int g = 0; g < 3; ++g)
            #pragma unroll
            for (int t = 0; t < 2; ++t)
                acc[g][t] = __builtin_amdgcn_mfma_scale_f32_32x32x64_f8f6f4(
                    afC[t], bfC[g], acc[g][t],
                    0, 0,                     // cbsz=fp8(A), blgp=fp8(B)
                    0, 0x7F7F7F7F,            // A scale = 1.0
                    0, 0x7B7B7B7B);           // B scale = 2^-4 (w stored x16)
        __builtin_amdgcn_s_setprio(0);
    }

    // --- epilogue: exp-form chain + column (s) reduction ------------------
    // C/D 32x32 layout: col = lane&31, row = (reg&3) + 8*(reg>>2) + 4*half
    const int b = panel >> 5;
    __syncthreads();                       // all LDS traffic done; reuse smem
    float* colsum = (float*)smem;
    if (tid < BN) colsum[tid] = 0.f;
    __syncthreads();

    float vsum = 0.f;
    #pragma unroll
    for (int t = 0; t < 2; ++t) {
        f32x16 fv = acc[0][t], iv = acc[1][t], hv = acc[2][t];
        #pragma unroll
        for (int r = 0; r < 16; ++r) {
            float ef = __expf(-fv[r]);
            float ei = __expf(-iv[r]);
            float h  = hv[r];
            float eh = __expf(h);
            float g  = (h >= 0.f) ? (h + 0.5f)
                                  : (eh * __builtin_amdgcn_rcpf(1.f + eh));
            vsum += (1.f + ef) * __builtin_amdgcn_rcpf(1.f + ei) * g;
        }
    }
    vsum += __shfl_xor(vsum, 32, 64);
    if (half == 0) atomicAdd(&colsum[wn * 32 + l31], vsum);
    __syncthreads();
    if (tid < BN)
        atomicAdd(&acc_ws[(size_t)b * H_ + h0 + tid], colsum[tid]);
}

// out[b,o] = b_out[o] + sum_h w_out[o,h] * F[b,h]*(0.5 + acc[b,h])
__global__ __launch_bounds__(256) void out_gemv(
    const float* __restrict__ wout, const float* __restrict__ bout,
    const float* __restrict__ acc_ws, const float* __restrict__ F_ws,
    float* __restrict__ out)
{
    const int lane = threadIdx.x & 63;
    const int o = blockIdx.x * 4 + (threadIdx.x >> 6);
    float s[B_] = {};
    for (int h = lane; h < H_; h += 64) {
        float w = wout[(size_t)o * H_ + h];
        #pragma unroll
        for (int b = 0; b < B_; ++b) {
            float hv = F_ws[b * H_ + h] * (0.5f + acc_ws[b * H_ + h]);
            s[b] = fmaf(w, hv, s[b]);
        }
    }
    #pragma unroll
    for (int b = 0; b < B_; ++b)
        #pragma unroll
        for (int off = 32; off > 0; off >>= 1)
            s[b] += __shfl_down(s[b], off, 64);
    if (lane == 0) {
        float bo = bout[o];
        #pragma unroll
        for (int b = 0; b < B_; ++b)
            out[(size_t)b * O_ + o] = s[b] + bo;
    }
}

// ---------------------------------------------------------------------------
// fp32 fallback (round-1 kernel) -- used only if ws_size is too small
// ---------------------------------------------------------------------------
constexpr int TS = 64, TH = 64, TK = 16, LDP = 68;

__global__ __launch_bounds__(256) void fused_gemm_reduce(
    const float* __restrict__ x, const float* __restrict__ win,
    float* __restrict__ acc_ws, float* __restrict__ F_ws)
{
    __shared__ __align__(16) float As[TK][LDP];
    __shared__ __align__(16) float Wf[TK][LDP];
    __shared__ __align__(16) float Wi[TK][LDP];
    __shared__ __align__(16) float Wh[TK][LDP];
    __shared__ float colsum[TH];

    const int b  = blockIdx.z;
    const int s0 = blockIdx.x * TS;
    const int h0 = blockIdx.y * TH;
    const int tid = threadIdx.x;
    const int tx = tid & 15;
    const int ty = tid >> 4;

    float accf[4][4] = {};
    float acci[4][4] = {};
    float acch[4][4] = {};

    const int lrow = tid >> 2;
    const int lk4  = (tid & 3) << 2;

    const float* xp  = x   + ((size_t)b * S_ + (s0 + lrow)) * D_ + lk4;
    const float* wfp = win + (size_t)(h0 + lrow) * D_ + lk4;
    const float* wip = wfp + (size_t)H_ * D_;
    const float* whp = wip + (size_t)H_ * D_;

    for (int k0 = 0; k0 < D_; k0 += TK) {
        float4 va = *(const float4*)(xp  + k0);
        float4 vf = *(const float4*)(wfp + k0);
        float4 vi = *(const float4*)(wip + k0);
        float4 vh = *(const float4*)(whp + k0);
        __syncthreads();
        As[lk4+0][lrow]=va.x; As[lk4+1][lrow]=va.y; As[lk4+2][lrow]=va.z; As[lk4+3][lrow]=va.w;
        Wf[lk4+0][lrow]=vf.x; Wf[lk4+1][lrow]=vf.y; Wf[lk4+2][lrow]=vf.z; Wf[lk4+3][lrow]=vf.w;
        Wi[lk4+0][lrow]=vi.x; Wi[lk4+1][lrow]=vi.y; Wi[lk4+2][lrow]=vi.z; Wi[lk4+3][lrow]=vi.w;
        Wh[lk4+0][lrow]=vh.x; Wh[lk4+1][lrow]=vh.y; Wh[lk4+2][lrow]=vh.z; Wh[lk4+3][lrow]=vh.w;
        __syncthreads();
        #pragma unroll
        for (int k = 0; k < TK; ++k) {
            float4 a4 = *(const float4*)&As[k][ty << 2];
            float4 f4 = *(const float4*)&Wf[k][tx << 2];
            float4 i4 = *(const float4*)&Wi[k][tx << 2];
            float4 h4 = *(const float4*)&Wh[k][tx << 2];
            float a[4]  = {a4.x, a4.y, a4.z, a4.w};
            float wf[4] = {f4.x, f4.y, f4.z, f4.w};
            float wi[4] = {i4.x, i4.y, i4.z, i4.w};
            float wh[4] = {h4.x, h4.y, h4.z, h4.w};
            #pragma unroll
            for (int r = 0; r < 4; ++r)
                #pragma unroll
                for (int cc = 0; cc < 4; ++cc) {
                    accf[r][cc] = fmaf(a[r], wf[cc], accf[r][cc]);
                    acci[r][cc] = fmaf(a[r], wi[cc], acci[r][cc]);
                    acch[r][cc] = fmaf(a[r], wh[cc], acch[r][cc]);
                }
        }
    }

    const bool last_s = (s0 + TS == S_);
    float cval[4] = {0.f, 0.f, 0.f, 0.f};
    #pragma unroll
    for (int cc = 0; cc < 4; ++cc)
        #pragma unroll
        for (int r = 0; r < 4; ++r) {
            float f = accf[r][cc], i = acci[r][cc], h = acch[r][cc];
            float d  = softplusf(-f) - softplusf(-i);
            float lg = (h >= 0.f) ? logf(h + 0.5f) : -softplusf(-h);
            cval[cc] += expf(d + lg);
            if (last_s && ty == 15 && r == 3)
                F_ws[(size_t)b * H_ + h0 + (tx << 2) + cc] = expf(-softplusf(d));
        }
    if (tid < TH) colsum[tid] = 0.f;
    __syncthreads();
    #pragma unroll
    for (int cc = 0; cc < 4; ++cc)
        atomicAdd(&colsum[(tx << 2) + cc], cval[cc]);
    __syncthreads();
    if (tid < TH)
        atomicAdd(&acc_ws[(size_t)b * H_ + h0 + tid], colsum[tid]);
}

extern "C" void kernel_launch(void* const* d_in, const int* in_sizes, int n_in,
                              void* d_out, int out_size, void* d_ws, size_t ws_size,
                              hipStream_t stream) {
    const float* x    = (const float*)d_in[0];
    const float* w_in = (const float*)d_in[1];
    const float* wout = (const float*)d_in[2];
    const float* bout = (const float*)d_in[3];
    float* out = (float*)d_out;

    float* acc_ws = (float*)d_ws;                 // [B,H] running sums
    float* F_ws   = acc_ws + (size_t)B_ * H_;     // [B,H] exact forget factor

    hipMemsetAsync(d_ws, 0, 2 * (size_t)B_ * H_ * sizeof(float), stream);

    const size_t nx = (size_t)B_ * S_ * D_;       // 33.5M
    const size_t nw = (size_t)3 * H_ * D_;        // 3.1M
    const size_t q_off = 32768;                   // past acc/F, 16B aligned
    const size_t need = q_off + nx + nw;          // fp8: 1 byte/elem

    if (ws_size >= need) {
        unsigned char* xq = (unsigned char*)d_ws + q_off;   // tiled layout
        unsigned char* wq = xq + nx;
        int nw8 = (int)(nw / 8);

        static int attr_done = 0;
        if (!attr_done) {
            (void)hipFuncSetAttribute((const void*)gemm_fused_fp8,
                hipFuncAttributeMaxDynamicSharedMemorySize, SMEM_BYTES);
            attr_done = 1;
        }

        cvt_x_tiled<<<128 * 4, 256, 0, stream>>>(x, xq);
        cvt_w8<<<(nw8 + 255) / 256, 256, 0, stream>>>(w_in, wq, nw8);
        f_exact<<<B_ * H_ / 4, 256, 0, stream>>>(x, w_in, F_ws);
        gemm_fused_fp8<<<(H_ / BN) * ((B_ * S_) / BM), 512, SMEM_BYTES, stream>>>(
            xq, wq, acc_ws);
    } else {
        dim3 grid(S_ / TS, H_ / TH, B_);
        fused_gemm_reduce<<<grid, 256, 0, stream>>>(x, w_in, acc_ws, F_ws);
    }
    out_gemv<<<O_ / 4, 256, 0, stream>>>(wout, bout, acc_ws, F_ws, out);
}

// Round 6
// 689.788 us; speedup vs baseline: 1.0219x; 1.0219x over previous
//
#include <hip/hip_runtime.h>
#include <math.h>

// Problem constants (fixed by setup_inputs)
constexpr int B_ = 4, S_ = 8192, D_ = 1024, H_ = 1024, O_ = 1024;

typedef float f32x4  __attribute__((ext_vector_type(4)));
typedef float f32x16 __attribute__((ext_vector_type(16)));
typedef int   i32x4  __attribute__((ext_vector_type(4)));
typedef int   i32x8  __attribute__((ext_vector_type(8)));

__device__ __forceinline__ float softplusf(float x) {
    if (x > 20.f) return x;
    if (x < -20.f) return expf(x);
    return log1pf(expf(x));
}

// ---------------------------------------------------------------------------
// fp32 -> fp8 e4m3 for x, written in MFMA-fragment-tiled order:
//   addr = pp*262144 + c*16384 + (r>>5)*2048 + j*1024 + (half*32 + (r&31))*16
//   (pp = s-panel of 256 rows, c = k-chunk of 64, j = k-bit4, half = k-bit5).
//   GEMM A-loads become base + lane*16 (fully coalesced dwordx4), no LDS
//   round-trip for A.  Byte-exact vs the round-3 (passing) LDS addressing.
// ---------------------------------------------------------------------------
__global__ __launch_bounds__(256) void cvt_x_tiled(
    const float* __restrict__ x, unsigned char* __restrict__ xq)
{
    const int blk = blockIdx.x;          // pp*4 + rq
    const int pp  = blk >> 2;
    const int rq  = blk & 3;
    const int rl  = threadIdx.x >> 2;    // 0..63
    const int seg = threadIdx.x & 3;     // 16-float segment within 64-k chunk
    const int r   = rq * 64 + rl;        // 0..255 (row within panel)

    const float* src = x + ((size_t)(pp * 256 + r)) * 1024 + seg * 16;
    unsigned char* dst = xq + (size_t)pp * 262144
                       + (r >> 5) * 2048 + (seg & 1) * 1024
                       + (((seg >> 1) * 32 + (r & 31))) * 16;
    #pragma unroll 4
    for (int c = 0; c < 16; ++c) {
        const float4* s4 = (const float4*)(src + c * 64);
        float4 f0 = s4[0], f1 = s4[1], f2 = s4[2], f3 = s4[3];
        int d0 = __builtin_amdgcn_cvt_pk_fp8_f32(f0.x, f0.y, 0, false);
        d0     = __builtin_amdgcn_cvt_pk_fp8_f32(f0.z, f0.w, d0, true);
        int d1 = __builtin_amdgcn_cvt_pk_fp8_f32(f1.x, f1.y, 0, false);
        d1     = __builtin_amdgcn_cvt_pk_fp8_f32(f1.z, f1.w, d1, true);
        int d2 = __builtin_amdgcn_cvt_pk_fp8_f32(f2.x, f2.y, 0, false);
        d2     = __builtin_amdgcn_cvt_pk_fp8_f32(f2.z, f2.w, d2, true);
        int d3 = __builtin_amdgcn_cvt_pk_fp8_f32(f3.x, f3.y, 0, false);
        d3     = __builtin_amdgcn_cvt_pk_fp8_f32(f3.z, f3.w, d3, true);
        *(int4*)(dst + (size_t)c * 16384) = make_int4(d0, d1, d2, d3);
    }
}

// fp32 -> fp8 e4m3 for w_in (scale 16, compensated by 2^-4 B-scale in MFMA),
// row-major (LDS-staged in the GEMM). 8 elems/thread.
__global__ __launch_bounds__(256) void cvt_w8(
    const float* __restrict__ src, unsigned char* __restrict__ dst, int n8)
{
    int i = blockIdx.x * blockDim.x + threadIdx.x;
    if (i >= n8) return;
    const float4* s = (const float4*)src + (size_t)i * 2;
    float4 a = s[0], b = s[1];
    int lo = __builtin_amdgcn_cvt_pk_fp8_f32(a.x * 16.f, a.y * 16.f, 0, false);
    lo     = __builtin_amdgcn_cvt_pk_fp8_f32(a.z * 16.f, a.w * 16.f, lo, true);
    int hi = __builtin_amdgcn_cvt_pk_fp8_f32(b.x * 16.f, b.y * 16.f, 0, false);
    hi     = __builtin_amdgcn_cvt_pk_fp8_f32(b.z * 16.f, b.w * 16.f, hi, true);
    ((int2*)dst)[i] = make_int2(lo, hi);
}

// ---------------------------------------------------------------------------
// Exact F in fp32 (one wave per (b,h)):
//   F = (1+e^{-i}) / ((1+e^{-f}) + (1+e^{-i}))  at s = S-1
// ---------------------------------------------------------------------------
__global__ __launch_bounds__(256) void f_exact(
    const float* __restrict__ x, const float* __restrict__ w_in,
    float* __restrict__ F_ws)
{
    const int lane = threadIdx.x & 63;
    const int pair = blockIdx.x * 4 + (threadIdx.x >> 6);   // 0..4095
    const int b = pair >> 10, h = pair & (H_ - 1);
    const float* xr = x + ((size_t)b * S_ + (S_ - 1)) * D_;
    const float* wf = w_in + (size_t)h * D_;
    const float* wi = wf + (size_t)H_ * D_;
    float sf = 0.f, si = 0.f;
    for (int k = lane; k < D_; k += 64) {
        float xv = xr[k];
        sf = fmaf(xv, wf[k], sf);
        si = fmaf(xv, wi[k], si);
    }
    #pragma unroll
    for (int off = 32; off > 0; off >>= 1) {
        sf += __shfl_xor(sf, off, 64);
        si += __shfl_xor(si, off, 64);
    }
    if (lane == 0) {
        float af1 = 1.f + expf(-sf), ai1 = 1.f + expf(-si);
        F_ws[(size_t)b * H_ + h] = ai1 / (af1 + ai1);
    }
}

// ---------------------------------------------------------------------------
// MX-fp8 MFMA GEMM (z = x @ w_in^T, 3 gates) fused with elementwise chain and
// s-reduction.
//   Round-6 = round-5 design, spill-proofed (R5 regressed to 514us on 1 GB
//   of scratch writes; VGPR clamped at exactly 128 = the cap that the
//   blocks-per-CU reading of launch_bounds' 2nd arg implies):
//   (1) __launch_bounds__(512, 1): cap 256 regs/wave under either semantics
//       (a 512-thread block can never exceed 2048/8 = 256 anyway).
//   (2) main loop = 8 iterations x {even half, odd half} with NAMED register
//       sets afE/bfE and afO/bfO (no runtime-selected pointers, rule #20).
//   (3) re-derived vmcnt ledger incl. k=7 even-half = vmcnt(8) (not 12).
//   Design: A bypasses LDS (fragment-tiled global loads, L1/L2-hot); LDS
//   stages ONLY B: 12 KB/chunk, 4-deep ring (48 KB). LDS traffic/chunk
//   drops 108KB -> 60KB (below the ~825-cy MFMA floor per CU).
// ---------------------------------------------------------------------------
constexpr int BM = 256, BN = 64, BK = 64;          // BK in fp8 bytes
constexpr int BUF_BYTES = 3 * BN * BK;             // 12288 (B only)
constexpr int NBUF = 4;
constexpr int SMEM_BYTES = NBUF * BUF_BYTES;       // 49152

__global__ __launch_bounds__(512, 1) void gemm_fused_fp8(
    const unsigned char* __restrict__ xq, const unsigned char* __restrict__ wq,
    float* __restrict__ acc_ws)
{
    extern __shared__ unsigned char smem[];        // 48 KB ring (4 B-buffers)

    // decode: id = ((pl*16 + hb) * 8) + c8 ; panel = c8*16 + pl
    // (16 h-tiles sharing an A panel -> same XCD under round-robin mod 8)
    const int id = blockIdx.x;
    const int c8 = id & 7;
    const int q  = id >> 3;
    const int hb = q & 15;
    const int pl = q >> 4;
    const int panel = c8 * 16 + pl;       // 0..127

    const int h0   = hb * BN;
    const int tid  = threadIdx.x;
    const int lane = tid & 63;
    const int wid  = tid >> 6;   // 0..7
    const int wm   = wid >> 1;   // 0..3 : s offset wm*64
    const int wn   = wid & 1;    // 0..1 : h offset wn*32
    const int l31  = lane & 31;
    const int half = lane >> 5;  // k-half for MFMA operand

    // --- B staging: v = wid*2 + j (wid<6); gate v>>2, rows (v&3)*16..+15 ---
    const unsigned char* gpb[2];
    {
        const int rl = lane >> 2;        // row within 16-row chunk
        const int sp = lane & 3;         // dest 16B slot within 64B row
        const int qq = sp ^ ((rl >> 1) & 3);   // swizzled source slot
        #pragma unroll
        for (int j = 0; j < 2; ++j) {
            int v = wid * 2 + j;         // 0..11 valid for wid<6
            if (v < 12) {
                gpb[j] = wq + (size_t)(v >> 2) * (H_ * D_)
                            + (size_t)(h0 + (v & 3) * 16 + rl) * D_ + qq * 16;
            } else {
                gpb[j] = wq;             // waves 6,7: never issued
            }
        }
    }

    // --- A: tiled global base (fragment layout; see cvt_x_tiled) ----------
    const unsigned char* abase = xq + (size_t)panel * 262144
                               + wm * 4096 + lane * 16;

    // --- B fragment byte-offsets (swizzle term g/t-independent) -----------
    const int g2 = (l31 >> 1) & 3;
    const int sA = ((half * 2) ^ g2) * 16;
    const int bof0  = (wn * 32 + l31) * 64 + sA;   // + g*4096
    const int bof0x = bof0 ^ 16;

    f32x16 acc[3][2] = {};   // [gate][m-tile]

    auto issueB = [&](int cc) {
        if (wid < 6) {
            unsigned char* lb = smem + (cc & 3) * BUF_BYTES + wid * 2048;
            #pragma unroll
            for (int j = 0; j < 2; ++j) {
                __builtin_amdgcn_global_load_lds(
                    (const __attribute__((address_space(1))) void*)gpb[j],
                    (__attribute__((address_space(3))) void*)(lb + j * 1024),
                    16, 0, 0);
                gpb[j] += BK;
            }
        }
    };
    auto ldA = [&](int cc, i32x8* af) {
        const unsigned char* p = abase + (size_t)cc * 16384;
        i32x4 a0 = *(const i32x4*)(p);
        i32x4 a1 = *(const i32x4*)(p + 1024);
        i32x4 a2 = *(const i32x4*)(p + 2048);
        i32x4 a3 = *(const i32x4*)(p + 3072);
        af[0] = (i32x8){a0.x, a0.y, a0.z, a0.w, a1.x, a1.y, a1.z, a1.w};
        af[1] = (i32x8){a2.x, a2.y, a2.z, a2.w, a3.x, a3.y, a3.z, a3.w};
    };
    auto rd8 = [](const unsigned char* base, int o0, int o1) -> i32x8 {
        i32x4 lo = *(const i32x4*)(base + o0);
        i32x4 hi = *(const i32x4*)(base + o1);
        i32x8 r = {lo.x, lo.y, lo.z, lo.w, hi.x, hi.y, hi.z, hi.w};
        return r;
    };
    auto ldB = [&](int cc, i32x8* bf) {
        const unsigned char* bp = smem + (cc & 3) * BUF_BYTES;
        bf[0] = rd8(bp, bof0,        bof0x);
        bf[1] = rd8(bp, bof0 + 4096, bof0x + 4096);
        bf[2] = rd8(bp, bof0 + 8192, bof0x + 8192);
    };
    auto mfma6 = [&](const i32x8* af, const i32x8* bf) {
        __builtin_amdgcn_s_setprio(1);
        #pragma unroll
        for (int g = 0; g < 3; ++g)
            #pragma unroll
            for (int t = 0; t < 2; ++t)
                acc[g][t] = __builtin_amdgcn_mfma_scale_f32_32x32x64_f8f6f4(
                    af[t], bf[g], acc[g][t],
                    0, 0,                     // cbsz=fp8(A), blgp=fp8(B)
                    0, 0x7F7F7F7F,            // A scale = 1.0
                    0, 0x7B7B7B7B);           // B scale = 2^-4 (w stored x16)
        __builtin_amdgcn_s_setprio(0);
    };

    i32x8 afE[2], afO[2], bfE[3], bfO[3];    // named even/odd sets ONLY

    // --- prologue: A(0) + D(0),D(1),D(2) in flight; frags of chunk 0 ------
    ldA(0, afE);                 // FIFO (wid<6): A0(4), D0(2), D1(2), D2(2)
    issueB(0); issueB(1); issueB(2);
    // drain A0+D0 (oldest 6 of 10) -> vmcnt(4).  wid>=6: A0(4) only, passes.
    asm volatile("s_waitcnt vmcnt(4)" ::: "memory");
    __builtin_amdgcn_sched_barrier(0);
    __builtin_amdgcn_s_barrier();          // all waves' D(0) landed
    __builtin_amdgcn_sched_barrier(0);
    ldB(0, bfE);

    // vmcnt ledger (wid<6).  Body(k): even chunk c=2k (regs E), odd d=2k+1
    // (regs O).  Even-half wait needs D(c+1) landed; odd-half needs D(d+1).
    //   even: k==0 -> 8   (entry [D1,D2]=4, +A1+D3=10, leave [D2,A1,D3]+... =8)
    //         1<=k<=6 -> 12 (entry 8, +A(c+1)+D(c+3)=14, leave 12)
    //         k==7 -> 8   (entry [D15,A14]=6, +A15=10, leave [A14,A15]=8)
    //   odd:  k<=5 -> 12 ; k==6 -> 10 ; k==7 none (last chunk, no reload)
    // Compiler's own waits for ldA consumption retire older DMAs early —
    // strictly safe.  wid>=6 waves carry only own A-loads (<=8): all pass.
    // Ring safety: ldB(c) reads drained by lgkmcnt(0) before barrier(c);
    // overwrite issueB(c+4) is post-barrier(c).
    constexpr int NC = D_ / BK;   // 16 chunks
    for (int k = 0; k < NC / 2; ++k) {
        const int c = 2 * k, d = 2 * k + 1;

        // ---------------- even half: compute chunk c on (afE,bfE) ---------
        ldA(c + 1, afO);                       // c+1 <= 15 always
        if (c + 3 < NC) issueB(c + 3);
        if (wid < 6) {
            if (k == 0 || k == 7) { asm volatile("s_waitcnt vmcnt(8)"  ::: "memory"); }
            else                  { asm volatile("s_waitcnt vmcnt(12)" ::: "memory"); }
        } else {
            asm volatile("s_waitcnt vmcnt(8)" ::: "memory");
        }
        asm volatile("s_waitcnt lgkmcnt(0)" ::: "memory");
        __builtin_amdgcn_sched_barrier(0);
        __builtin_amdgcn_s_barrier();          // all waves' D(c+1) landed
        __builtin_amdgcn_sched_barrier(0);
        ldB(c + 1, bfO);                       // hides under MFMAs below
        mfma6(afE, bfE);

        // ---------------- odd half: compute chunk d on (afO,bfO) ----------
        if (d + 1 < NC) {
            ldA(d + 1, afE);
            if (d + 3 < NC) issueB(d + 3);
            if (wid < 6) {
                if (k <= 5) { asm volatile("s_waitcnt vmcnt(12)" ::: "memory"); }
                else        { asm volatile("s_waitcnt vmcnt(10)" ::: "memory"); }
            } else {
                asm volatile("s_waitcnt vmcnt(8)" ::: "memory");
            }
            asm volatile("s_waitcnt lgkmcnt(0)" ::: "memory");
            __builtin_amdgcn_sched_barrier(0);
            __builtin_amdgcn_s_barrier();      // all waves' D(d+1) landed
            __builtin_amdgcn_sched_barrier(0);
            ldB(d + 1, bfE);
        }
        mfma6(afO, bfO);
    }

    // --- epilogue: exp-form chain + column (s) reduction ------------------
    // C/D 32x32 layout: col = lane&31, row = (reg&3) + 8*(reg>>2) + 4*half
    const int b = panel >> 5;
    __syncthreads();                       // all LDS traffic done; reuse smem
    float* colsum = (float*)smem;
    if (tid < BN) colsum[tid] = 0.f;
    __syncthreads();

    float vsum = 0.f;
    #pragma unroll
    for (int t = 0; t < 2; ++t) {
        f32x16 fv = acc[0][t], iv = acc[1][t], hv = acc[2][t];
        #pragma unroll
        for (int r = 0; r < 16; ++r) {
            float ef = __expf(-fv[r]);
            float ei = __expf(-iv[r]);
            float h  = hv[r];
            float eh = __expf(h);
            float g  = (h >= 0.f) ? (h + 0.5f)
                                  : (eh * __builtin_amdgcn_rcpf(1.f + eh));
            vsum += (1.f + ef) * __builtin_amdgcn_rcpf(1.f + ei) * g;
        }
    }
    vsum += __shfl_xor(vsum, 32, 64);
    if (half == 0) atomicAdd(&colsum[wn * 32 + l31], vsum);
    __syncthreads();
    if (tid < BN)
        atomicAdd(&acc_ws[(size_t)b * H_ + h0 + tid], colsum[tid]);
}

// out[b,o] = b_out[o] + sum_h w_out[o,h] * F[b,h]*(0.5 + acc[b,h])
__global__ __launch_bounds__(256) void out_gemv(
    const float* __restrict__ wout, const float* __restrict__ bout,
    const float* __restrict__ acc_ws, const float* __restrict__ F_ws,
    float* __restrict__ out)
{
    const int lane = threadIdx.x & 63;
    const int o = blockIdx.x * 4 + (threadIdx.x >> 6);
    float s[B_] = {};
    for (int h = lane; h < H_; h += 64) {
        float w = wout[(size_t)o * H_ + h];
        #pragma unroll
        for (int b = 0; b < B_; ++b) {
            float hv = F_ws[b * H_ + h] * (0.5f + acc_ws[b * H_ + h]);
            s[b] = fmaf(w, hv, s[b]);
        }
    }
    #pragma unroll
    for (int b = 0; b < B_; ++b)
        #pragma unroll
        for (int off = 32; off > 0; off >>= 1)
            s[b] += __shfl_down(s[b], off, 64);
    if (lane == 0) {
        float bo = bout[o];
        #pragma unroll
        for (int b = 0; b < B_; ++b)
            out[(size_t)b * O_ + o] = s[b] + bo;
    }
}

// ---------------------------------------------------------------------------
// fp32 fallback (round-1 kernel) -- used only if ws_size is too small
// ---------------------------------------------------------------------------
constexpr int TS = 64, TH = 64, TK = 16, LDP = 68;

__global__ __launch_bounds__(256) void fused_gemm_reduce(
    const float* __restrict__ x, const float* __restrict__ win,
    float* __restrict__ acc_ws, float* __restrict__ F_ws)
{
    __shared__ __align__(16) float As[TK][LDP];
    __shared__ __align__(16) float Wf[TK][LDP];
    __shared__ __align__(16) float Wi[TK][LDP];
    __shared__ __align__(16) float Wh[TK][LDP];
    __shared__ float colsum[TH];

    const int b  = blockIdx.z;
    const int s0 = blockIdx.x * TS;
    const int h0 = blockIdx.y * TH;
    const int tid = threadIdx.x;
    const int tx = tid & 15;
    const int ty = tid >> 4;

    float accf[4][4] = {};
    float acci[4][4] = {};
    float acch[4][4] = {};

    const int lrow = tid >> 2;
    const int lk4  = (tid & 3) << 2;

    const float* xp  = x   + ((size_t)b * S_ + (s0 + lrow)) * D_ + lk4;
    const float* wfp = win + (size_t)(h0 + lrow) * D_ + lk4;
    const float* wip = wfp + (size_t)H_ * D_;
    const float* whp = wip + (size_t)H_ * D_;

    for (int k0 = 0; k0 < D_; k0 += TK) {
        float4 va = *(const float4*)(xp  + k0);
        float4 vf = *(const float4*)(wfp + k0);
        float4 vi = *(const float4*)(wip + k0);
        float4 vh = *(const float4*)(whp + k0);
        __syncthreads();
        As[lk4+0][lrow]=va.x; As[lk4+1][lrow]=va.y; As[lk4+2][lrow]=va.z; As[lk4+3][lrow]=va.w;
        Wf[lk4+0][lrow]=vf.x; Wf[lk4+1][lrow]=vf.y; Wf[lk4+2][lrow]=vf.z; Wf[lk4+3][lrow]=vf.w;
        Wi[lk4+0][lrow]=vi.x; Wi[lk4+1][lrow]=vi.y; Wi[lk4+2][lrow]=vi.z; Wi[lk4+3][lrow]=vi.w;
        Wh[lk4+0][lrow]=vh.x; Wh[lk4+1][lrow]=vh.y; Wh[lk4+2][lrow]=vh.z; Wh[lk4+3][lrow]=vh.w;
        __syncthreads();
        #pragma unroll
        for (int k = 0; k < TK; ++k) {
            float4 a4 = *(const float4*)&As[k][ty << 2];
            float4 f4 = *(const float4*)&Wf[k][tx << 2];
            float4 i4 = *(const float4*)&Wi[k][tx << 2];
            float4 h4 = *(const float4*)&Wh[k][tx << 2];
            float a[4]  = {a4.x, a4.y, a4.z, a4.w};
            float wf[4] = {f4.x, f4.y, f4.z, f4.w};
            float wi[4] = {i4.x, i4.y, i4.z, i4.w};
            float wh[4] = {h4.x, h4.y, h4.z, h4.w};
            #pragma unroll
            for (int r = 0; r < 4; ++r)
                #pragma unroll
                for (int cc = 0; cc < 4; ++cc) {
                    accf[r][cc] = fmaf(a[r], wf[cc], accf[r][cc]);
                    acci[r][cc] = fmaf(a[r], wi[cc], acci[r][cc]);
                    acch[r][cc] = fmaf(a[r], wh[cc], acch[r][cc]);
                }
        }
    }

    const bool last_s = (s0 + TS == S_);
    float cval[4] = {0.f, 0.f, 0.f, 0.f};
    #pragma unroll
    for (int cc = 0; cc < 4; ++cc)
        #pragma unroll
        for (int r = 0; r < 4; ++r) {
            float f = accf[r][cc], i = acci[r][cc], h = acch[r][cc];
            float d  = softplusf(-f) - softplusf(-i);
            float lg = (h >= 0.f) ? logf(h + 0.5f) : -softplusf(-h);
            cval[cc] += expf(d + lg);
            if (last_s && ty == 15 && r == 3)
                F_ws[(size_t)b * H_ + h0 + (tx << 2) + cc] = expf(-softplusf(d));
        }
    if (tid < TH) colsum[tid] = 0.f;
    __syncthreads();
    #pragma unroll
    for (int cc = 0; cc < 4; ++cc)
        atomicAdd(&colsum[(tx << 2) + cc], cval[cc]);
    __syncthreads();
    if (tid < TH)
        atomicAdd(&acc_ws[(size_t)b * H_ + h0 + tid], colsum[tid]);
}

extern "C" void kernel_launch(void* const* d_in, const int* in_sizes, int n_in,
                              void* d_out, int out_size, void* d_ws, size_t ws_size,
                              hipStream_t stream) {
    const float* x    = (const float*)d_in[0];
    const float* w_in = (const float*)d_in[1];
    const float* wout = (const float*)d_in[2];
    const float* bout = (const float*)d_in[3];
    float* out = (float*)d_out;

    float* acc_ws = (float*)d_ws;                 // [B,H] running sums
    float* F_ws   = acc_ws + (size_t)B_ * H_;     // [B,H] exact forget factor

    hipMemsetAsync(d_ws, 0, 2 * (size_t)B_ * H_ * sizeof(float), stream);

    const size_t nx = (size_t)B_ * S_ * D_;       // 33.5M
    const size_t nw = (size_t)3 * H_ * D_;        // 3.1M
    const size_t q_off = 32768;                   // past acc/F, 16B aligned
    const size_t need = q_off + nx + nw;          // fp8: 1 byte/elem

    if (ws_size >= need) {
        unsigned char* xq = (unsigned char*)d_ws + q_off;   // tiled layout
        unsigned char* wq = xq + nx;
        int nw8 = (int)(nw / 8);

        static int attr_done = 0;
        if (!attr_done) {
            (void)hipFuncSetAttribute((const void*)gemm_fused_fp8,
                hipFuncAttributeMaxDynamicSharedMemorySize, SMEM_BYTES);
            attr_done = 1;
        }

        cvt_x_tiled<<<128 * 4, 256, 0, stream>>>(x, xq);
        cvt_w8<<<(nw8 + 255) / 256, 256, 0, stream>>>(w_in, wq, nw8);
        f_exact<<<B_ * H_ / 4, 256, 0, stream>>>(x, w_in, F_ws);
        gemm_fused_fp8<<<(H_ / BN) * ((B_ * S_) / BM), 512, SMEM_BYTES, stream>>>(
            xq, wq, acc_ws);
    } else {
        dim3 grid(S_ / TS, H_ / TH, B_);
        fused_gemm_reduce<<<grid, 256, 0, stream>>>(x, w_in, acc_ws, F_ws);
    }
    out_gemv<<<O_ / 4, 256, 0, stream>>>(wout, bout, acc_ws, F_ws, out);
}